// Round 16
// baseline (1858.737 us; speedup 1.0000x reference)
//
#include <hip/hip_runtime.h>

// SineLSTM: 2-layer LSTM (H=50), B=512 rows, one row per block.
// R18 = R17's layer pipeline (1064us, best) with the work spread 2x thinner.
//   R17 post-mortem: tick pace set by the consumer wave (100 dot2 + refresh
//   + act); 2 waves/SIMD. Fix: TB=512, waves 0-3 = layer1, waves 4-7 =
//   layer2, quad-lane gate mapping (lane 4m+q owns gate row q*50+m -- ONE
//   row/lane): L2 = 50 dot2/lane, L1 = 25. Gate exchange = 3 __shfl_xor in
//   the quad (R6/R11-proven numerics; wave-uniform exec -- no R8 hazard).
//   ~120 VGPR (50 weight half2 + 50 carries): if <=128, same grid gives
//   16 waves/CU = 4 waves/SIMD (2x R17's occupancy).
//   All else R17 verbatim: step-parity ring h buffers (single writer, every
//   store->read crosses a barrier -- no TBAA fence needed), 1 barrier per
//   teacher tick, wave0 deferred out(t-2), predict ticks add barrier B for
//   the o feedback, producers skip the h2 refresh.
// Hazard audit (same slots as R17): h1lds[t&1] W@t -> R@t+1 (refresh), WAR
//   R@t-1 vs W@t: barrier(t) separates. h2lds/h2f32[(t+1)&1] W@t -> R@t+1
//   (refresh/deferred) and R@t post-B (predict); WAR R@t-1 vs W@t: ok.
// Numerics bitwise = R17: DOT25 4-acc order, (a0+a2)+(a1+a3), L2 = b2 +
//   wi2-sweep + wh2-sweep, same activations, f16 cast points, reduce tree.

#define Hh   50
#define TLEN 1024

typedef _Float16 half2v __attribute__((ext_vector_type(2)));

#if __has_builtin(__builtin_amdgcn_fdot2)
#define FDOT2(a, b, c) __builtin_amdgcn_fdot2((a), (b), (c), false)
#else
#define FDOT2(a, b, c) ((c) + (float)(a)[0] * (float)(b)[0] + (float)(a)[1] * (float)(b)[1])
#endif

#define BC(f) __builtin_bit_cast(half2v, f)

// 25-pair dot, R17's exact accumulation order (p -> acc(p&3), pairs 0..24).
#define DOT25(A0, A1, A2, A3, W, H) do {                                     \
    _Pragma("unroll")                                                        \
    for (int pq = 0; pq < 6; ++pq) {                                         \
        A0 = FDOT2(W[4*pq + 0], BC(H[4*pq + 0]), A0);                        \
        A1 = FDOT2(W[4*pq + 1], BC(H[4*pq + 1]), A1);                        \
        A2 = FDOT2(W[4*pq + 2], BC(H[4*pq + 2]), A2);                        \
        A3 = FDOT2(W[4*pq + 3], BC(H[4*pq + 3]), A3);                        \
    }                                                                        \
    A0 = FDOT2(W[24], BC(H[24]), A0);                                        \
} while (0)

__device__ __forceinline__ float fast_sigmoid(float v) {
    return 1.0f / (1.0f + __expf(-v));
}
__device__ __forceinline__ float fast_tanh(float v) {
    return 1.0f - 2.0f / (__expf(2.0f * v) + 1.0f);
}

extern "C" __global__ __launch_bounds__(512, 2)
void sine_lstm_kernel(const float* __restrict__ x,
                      const float* __restrict__ W_ih1,
                      const float* __restrict__ W_hh1,
                      const float* __restrict__ b_ih1,
                      const float* __restrict__ b_hh1,
                      const float* __restrict__ W_ih2,
                      const float* __restrict__ W_hh2,
                      const float* __restrict__ b_ih2,
                      const float* __restrict__ b_hh2,
                      const float* __restrict__ W_lin,
                      const float* __restrict__ b_lin,
                      const int*   __restrict__ predict_p,
                      float* __restrict__ out,
                      int T)
{
    __shared__ __align__(16) float    x_lds[TLEN];
    __shared__ __align__(16) _Float16 h1lds[2][64];   // ring: slot s&1 = h1(s)
    __shared__ __align__(16) _Float16 h2lds[2][64];   // ring: slot s&1 = h2(s)
    __shared__ __align__(16) float    h2f32[2][64];   // fp32 copy for outputs

    const int tid = threadIdx.x;           // 0..511
    const int wv  = tid >> 6;              // 0..3 = L1 (producer); 4..7 = L2
    const int ln  = tid & 63;
    const bool isProd = (wv < 4);
    const int b   = blockIdx.x;
    const int predict = *predict_p;
    const int S = T + predict;

    for (int i = tid; i < TLEN; i += 512)
        x_lds[i] = x[(size_t)b * T + i];
    if (tid < 128) {
        ((_Float16*)h1lds)[tid] = (_Float16)0.0f;
        ((_Float16*)h2lds)[tid] = (_Float16)0.0f;
        ((float*)h2f32)[tid] = 0.0f;
    }

    // quad mapping (R6): within each layer's 4 waves, lane group
    // m = (wv&3)*16 + (ln>>2) is the unit, q = ln&3 the gate; one row/lane.
    const int  m    = ((wv & 3) << 4) + (ln >> 2);   // 0..63
    const int  q    = ln & 3;
    const bool mval = (m < Hh);
    const bool lead = mval && (q == 0);    // owns unit m's cell state
    const int  rc   = mval ? (q * Hh + m) : 0;   // own gate row (clamped)

    // weights: L1: wA = W_hh1 row (wB dummy); L2: wA = W_ih2, wB = W_hh2.
    const float* MA = isProd ? W_hh1 : W_ih2;
    const float* MB = isProd ? W_hh1 : W_hh2;
    half2v wA[25], wB[25];
    #pragma unroll
    for (int p = 0; p < 25; ++p) {
        const int k0 = 2 * p, k1 = 2 * p + 1;
        wA[p] = half2v{(_Float16)MA[rc * Hh + k0], (_Float16)MA[rc * Hh + k1]};
        wB[p] = half2v{(_Float16)MB[rc * Hh + k0], (_Float16)MB[rc * Hh + k1]};
    }
    const float bR   = isProd ? (b_ih1[rc] + b_hh1[rc]) : (b_ih2[rc] + b_hh2[rc]);
    const float wihR = W_ih1[rc];          // used by producer only
    const float wlin_l = (ln < Hh) ? W_lin[ln] : 0.0f;
    const float blin   = b_lin[0];

    float h1r[25], h2r[25];                // f16-pair carries
    #pragma unroll
    for (int p = 0; p < 25; ++p) { h1r[p] = 0.0f; h2r[p] = 0.0f; }
    float cst = 0.0f;   // c1 on L1 lead lanes, c2 on L2 lead lanes

    __syncthreads();    // init complete

    for (int t = 0; t <= S; ++t) {
        __syncthreads();                   // tick barrier
        // ---- refresh carries: h1(t-1) for all; h2(t-2) for consumers ----
        {
            const int s1 = (t + 1) & 1;    // == (t-1)&1
            #pragma unroll
            for (int L = 0; L < 6; ++L) {
                float4 f = *(const float4*)&h1lds[s1][8 * L];
                h1r[4*L] = f.x; h1r[4*L+1] = f.y; h1r[4*L+2] = f.z; h1r[4*L+3] = f.w;
            }
            h1r[24] = *(const float*)&h1lds[s1][48];
        }
        if (!isProd) {
            const int s2 = t & 1;          // == (t-2)&1
            #pragma unroll
            for (int L = 0; L < 6; ++L) {
                float4 f = *(const float4*)&h2lds[s2][8 * L];
                h2r[4*L] = f.x; h2r[4*L+1] = f.y; h2r[4*L+2] = f.z; h2r[4*L+3] = f.w;
            }
            h2r[24] = *(const float*)&h2lds[s2][48];
        }
        const bool pred = (t >= T);

        // ---- consumer: G2+U2 for step t-1 (t>=1) ----
        if (!isProd && t >= 1) {
            float a0 = bR, a1 = 0.0f, a2 = 0.0f, a3 = 0.0f;
            DOT25(a0, a1, a2, a3, wA, h1r);     // wi2 sweep
            DOT25(a0, a1, a2, a3, wB, h2r);     // wh2 sweep
            float g  = (a0 + a2) + (a1 + a3);
            float v1 = __shfl_xor(g, 1);        // lead gets f
            float v2 = __shfl_xor(g, 2);        // lead gets g-gate
            float v3 = __shfl_xor(g, 3);        // lead gets o
            if (lead) {
                float cn = fast_sigmoid(v1) * cst + fast_sigmoid(g) * fast_tanh(v2);
                cst = cn;
                float hn = fast_sigmoid(v3) * fast_tanh(cn);
                h2lds[(t + 1) & 1][m] = (_Float16)hn;   // slot (t-1)&1
                h2f32[(t + 1) & 1][m] = hn;
            }
        }

        // ---- wave0: deferred out(t-2) from h2f32 ring ----
        if (wv == 0 && t >= 2 && t <= T) {
            float part = (ln < Hh) ? h2f32[t & 1][ln] * wlin_l : 0.0f;
            #pragma unroll
            for (int off = 32; off > 0; off >>= 1)
                part += __shfl_down(part, off);
            if (ln == 0) out[(size_t)b * S + (t - 2)] = part + blin;
        }

        if (!pred) {
            // ---- teacher: producer G1+U1 for step t ----
            if (isProd) {
                float xin = x_lds[t];
                float a0 = bR + xin * wihR, a1 = 0.0f, a2 = 0.0f, a3 = 0.0f;
                DOT25(a0, a1, a2, a3, wA, h1r);
                float g  = (a0 + a2) + (a1 + a3);
                float v1 = __shfl_xor(g, 1);
                float v2 = __shfl_xor(g, 2);
                float v3 = __shfl_xor(g, 3);
                if (lead) {
                    float cn = fast_sigmoid(v1) * cst + fast_sigmoid(g) * fast_tanh(v2);
                    cst = cn;
                    h1lds[t & 1][m] = (_Float16)(fast_sigmoid(v3) * fast_tanh(cn));
                }
            }
        } else {
            // ---- predict tick: consumer published h2(t-1); sync, make o ----
            __syncthreads();               // barrier B
            float part = (ln < Hh) ? h2f32[(t + 1) & 1][ln] * wlin_l : 0.0f;
            #pragma unroll
            for (int off = 32; off > 0; off >>= 1)
                part += __shfl_down(part, off);
            float o = __shfl(part, 0) + blin;
            if (tid == 0) out[(size_t)b * S + (t - 1)] = o;
            if (isProd && t < S) {         // producer G1(t) with xin = o(t-1)
                float a0 = bR + o * wihR, a1 = 0.0f, a2 = 0.0f, a3 = 0.0f;
                DOT25(a0, a1, a2, a3, wA, h1r);
                float g  = (a0 + a2) + (a1 + a3);
                float v1 = __shfl_xor(g, 1);
                float v2 = __shfl_xor(g, 2);
                float v3 = __shfl_xor(g, 3);
                if (lead) {
                    float cn = fast_sigmoid(v1) * cst + fast_sigmoid(g) * fast_tanh(v2);
                    cst = cn;
                    h1lds[t & 1][m] = (_Float16)(fast_sigmoid(v3) * fast_tanh(cn));
                }
            }
        }
    }
}

extern "C" void kernel_launch(void* const* d_in, const int* in_sizes, int n_in,
                              void* d_out, int out_size, void* d_ws, size_t ws_size,
                              hipStream_t stream) {
    const float* x      = (const float*)d_in[0];
    const float* W_ih1  = (const float*)d_in[1];
    const float* W_hh1  = (const float*)d_in[2];
    const float* b_ih1  = (const float*)d_in[3];
    const float* b_hh1  = (const float*)d_in[4];
    const float* W_ih2  = (const float*)d_in[5];
    const float* W_hh2  = (const float*)d_in[6];
    const float* b_ih2  = (const float*)d_in[7];
    const float* b_hh2  = (const float*)d_in[8];
    const float* W_lin  = (const float*)d_in[9];
    const float* b_lin  = (const float*)d_in[10];
    const int*   pred   = (const int*)d_in[11];
    float* out = (float*)d_out;

    const int B = 512;                 // fixed by setup_inputs
    const int T = in_sizes[0] / B;     // 1024

    dim3 grid(B), block(512);
    hipLaunchKernelGGL(sine_lstm_kernel, grid, block, 0, stream,
                       x, W_ih1, W_hh1, b_ih1, b_hh1,
                       W_ih2, W_hh2, b_ih2, b_hh2,
                       W_lin, b_lin, pred, out, T);
}